// Round 10
// baseline (252.264 us; speedup 1.0000x reference)
//
#include <hip/hip_runtime.h>
#include <cstdint>

#define NN 2048
#define DD 512
#define NB 8
#define NCAND 24
#define SSTR 138  // LDS S-tile row stride (ushorts); 69 dwords, 5 mod 32 -> 2-way max

using ull = unsigned long long;
typedef __attribute__((ext_vector_type(8))) short bf16x8;
typedef __attribute__((ext_vector_type(4))) float f32x4;

// async global->LDS, 16 B per lane; LDS dest = wave-uniform base + lane*16
#define GLOAD_LDS16(g, l)                                                      \
  __builtin_amdgcn_global_load_lds(                                            \
      (const __attribute__((address_space(1))) unsigned int*)(g),              \
      (__attribute__((address_space(3))) unsigned int*)(l), 16, 0, 0)

// float -> bf16 RNE (no NaN in this data)
__device__ inline unsigned short f2bf(float f) {
  unsigned u = __float_as_uint(f);
  unsigned r = u + 0x7FFFu + ((u >> 16) & 1u);
  return (unsigned short)(r >> 16);
}

#define CEX(a, i, j)                                                           \
  {                                                                            \
    unsigned lo_ = min(a[i], a[j]), hi_ = max(a[i], a[j]);                     \
    a[i] = lo_;                                                                \
    a[j] = hi_;                                                                \
  }

__device__ __forceinline__ void sort8(unsigned (&a)[8]) {  // Batcher, 19 CE
  CEX(a, 0, 1) CEX(a, 2, 3) CEX(a, 4, 5) CEX(a, 6, 7)
  CEX(a, 0, 2) CEX(a, 1, 3) CEX(a, 4, 6) CEX(a, 5, 7)
  CEX(a, 1, 2) CEX(a, 5, 6)
  CEX(a, 0, 4) CEX(a, 1, 5) CEX(a, 2, 6) CEX(a, 3, 7)
  CEX(a, 2, 4) CEX(a, 3, 5)
  CEX(a, 1, 2) CEX(a, 3, 4) CEX(a, 5, 6)
}

// a, b sorted asc -> a = sorted 8 smallest of the 16
__device__ __forceinline__ void merge8(unsigned (&a)[8], const unsigned (&b)[8]) {
  unsigned t[8];
#pragma unroll
  for (int i = 0; i < 8; ++i) t[i] = min(a[i], b[7 - i]);  // bitonic
  CEX(t, 0, 4) CEX(t, 1, 5) CEX(t, 2, 6) CEX(t, 3, 7)
  CEX(t, 0, 2) CEX(t, 1, 3) CEX(t, 4, 6) CEX(t, 5, 7)
  CEX(t, 0, 1) CEX(t, 2, 3) CEX(t, 4, 5) CEX(t, 6, 7)
#pragma unroll
  for (int i = 0; i < 8; ++i) a[i] = t[i];
}

__device__ __forceinline__ void load8(unsigned (&a)[8], const unsigned short* p,
                                      unsigned c0) {
  uint4 u = *(const uint4*)p;
  a[0] = (u.x << 16) | c0;
  a[1] = (u.x & 0xFFFF0000u) | (c0 + 1);
  a[2] = (u.y << 16) | (c0 + 2);
  a[3] = (u.y & 0xFFFF0000u) | (c0 + 3);
  a[4] = (u.z << 16) | (c0 + 4);
  a[5] = (u.z & 0xFFFF0000u) | (c0 + 5);
  a[6] = (u.w << 16) | (c0 + 6);
  a[7] = (u.w & 0xFFFF0000u) | (c0 + 7);
}

// Per-half-row exact top-8 of a 64-col S half-tile in LDS (stride SSTR).
// Thread t: row = t>>1, half = t&1. Streaming sort8 + merge8 (no shfl).
// Keys = (fp16bits << 16) | global_col (monotone, lower-index tie).
// Kws layout: [row][tile][half][8] -> 256 keys/row, coalesced uint4 in select.
__device__ __forceinline__ void sel_write(const unsigned short* S,
                                          unsigned* __restrict__ Kws, int b,
                                          int rowbase, int tile, int colbase,
                                          int t) {
  const int row = t >> 1, half = t & 1;
  const unsigned short* Sr = S + row * SSTR + half * 64;
  const unsigned cb = (unsigned)(colbase + half * 64);
  unsigned m[8], s1[8];
  load8(m, Sr, cb);
  sort8(m);
#pragma unroll
  for (int c = 8; c < 64; c += 8) {
    load8(s1, Sr + c, cb + c);
    sort8(s1);
    merge8(m, s1);
  }
  unsigned* dst =
      Kws + (((size_t)(b * NN + rowbase + row) * 16 + tile) << 4) + half * 8;
  uint4 v0, v1;
  v0.x = m[0]; v0.y = m[1]; v0.z = m[2]; v0.w = m[3];
  v1.x = m[4]; v1.y = m[5]; v1.z = m[6]; v1.w = m[7];
  ((uint4*)dst)[0] = v0;
  ((uint4*)dst)[1] = v1;
}

// ---------------------------------------------------------------------------
// Kernel 1: per-row fp32 norm (exact fp64 sum — validated chain) + bf16 copy.
// ---------------------------------------------------------------------------
__global__ __launch_bounds__(256) void knn_prep(const float* __restrict__ put,
                                                float* __restrict__ norms32,
                                                unsigned short* __restrict__ bhalf) {
  const int row  = blockIdx.x * 4 + (threadIdx.x >> 6);
  const int lane = threadIdx.x & 63;
  const float* p = put + (size_t)row * DD + lane * 8;
  float4 x0 = ((const float4*)p)[0];
  float4 x1 = ((const float4*)p)[1];
  double s = (double)x0.x * (double)x0.x + (double)x0.y * (double)x0.y +
             (double)x0.z * (double)x0.z + (double)x0.w * (double)x0.w +
             (double)x1.x * (double)x1.x + (double)x1.y * (double)x1.y +
             (double)x1.z * (double)x1.z + (double)x1.w * (double)x1.w;
  uint4 v;
  v.x = (unsigned)f2bf(x0.x) | ((unsigned)f2bf(x0.y) << 16);
  v.y = (unsigned)f2bf(x0.z) | ((unsigned)f2bf(x0.w) << 16);
  v.z = (unsigned)f2bf(x1.x) | ((unsigned)f2bf(x1.y) << 16);
  v.w = (unsigned)f2bf(x1.z) | ((unsigned)f2bf(x1.w) << 16);
  *((uint4*)(bhalf + (size_t)row * DD) + lane) = v;
#pragma unroll
  for (int m = 1; m < 64; m <<= 1) s += __shfl_xor(s, m, 64);
  if (lane == 0) norms32[row] = (float)s;
}

// ---------------------------------------------------------------------------
// Kernel 2: symmetric bf16 MFMA Gram + fused per-half-row top-8 key epilogue.
// S never hits HBM. Off-diagonal tiles run the epilogue twice (normal +
// mirrored). K-loop: validated m97-style global_load_lds + XOR swizzle.
// LDS S stride 138 (69 dwords, coprime-ish with 32 banks -> 2-way max,
// fixing round 9's 8-way conflict at stride 136).
// ---------------------------------------------------------------------------
__global__ __launch_bounds__(256) void knn_gemm(
    const unsigned short* __restrict__ bhalf,
    const float* __restrict__ norms32,
    unsigned* __restrict__ Kws) {
  __shared__ unsigned short smem[17664];  // 35328 B; K-loop: As/Bs; epi: S
  unsigned short* As = smem;              // 8 KB: 128 rows x 32 ushorts
  unsigned short* Bs = smem + 4096;       // 8 KB

  int idx = blockIdx.x;
  int jt = 0;
  while (idx >= 16 - jt) { idx -= 16 - jt; ++jt; }
  const int mt = jt + idx;

  const int t    = threadIdx.x;
  const int lane = t & 63;
  const int wv   = t >> 6;
  const int q    = lane >> 4;
  const int l15  = lane & 15;
  const int wrow = wv >> 1, wcol = wv & 1;
  const int m0 = mt * 128;
  const int j0 = jt * 128;
  const int b  = blockIdx.y;

  const unsigned short* pb = bhalf + (size_t)b * NN * DD;

  const int rloc = lane >> 2;
  const int kcg  = (lane & 3) ^ ((lane >> 3) & 3);
  const int i0 = 2 * wv, i1 = 2 * wv + 1;
  const unsigned short* gA0 = pb + (size_t)(j0 + 16 * i0 + rloc) * DD + kcg * 8;
  const unsigned short* gA1 = pb + (size_t)(j0 + 16 * i1 + rloc) * DD + kcg * 8;
  const unsigned short* gB0 = pb + (size_t)(m0 + 16 * i0 + rloc) * DD + kcg * 8;
  const unsigned short* gB1 = pb + (size_t)(m0 + 16 * i1 + rloc) * DD + kcg * 8;
  unsigned short* lA0 = As + i0 * 512;
  unsigned short* lA1 = As + i1 * 512;
  unsigned short* lB0 = Bs + i0 * 512;
  unsigned short* lB1 = Bs + i1 * 512;

  const int xsw = (q ^ ((l15 >> 1) & 3)) * 8;  // ushort offset

  f32x4 acc[4][4];
  const f32x4 zz = {0.f, 0.f, 0.f, 0.f};
#pragma unroll
  for (int i = 0; i < 4; ++i)
#pragma unroll
    for (int j = 0; j < 4; ++j) acc[i][j] = zz;

  for (int kt = 0; kt < DD; kt += 32) {
    __syncthreads();
    GLOAD_LDS16(gA0, lA0);
    GLOAD_LDS16(gA1, lA1);
    GLOAD_LDS16(gB0, lB0);
    GLOAD_LDS16(gB1, lB1);
    gA0 += 32; gA1 += 32; gB0 += 32; gB1 += 32;
    __syncthreads();

    bf16x8 af[4], bg[4];
#pragma unroll
    for (int f = 0; f < 4; ++f) {
      af[f] = *(const bf16x8*)(As + (wrow * 64 + f * 16 + l15) * 32 + xsw);
      bg[f] = *(const bf16x8*)(Bs + (wcol * 64 + f * 16 + l15) * 32 + xsw);
    }
#pragma unroll
    for (int fi = 0; fi < 4; ++fi)
#pragma unroll
      for (int fj = 0; fj < 4; ++fj)
        acc[fi][fj] = __builtin_amdgcn_mfma_f32_16x16x32_bf16(
            af[fi], bg[fj], acc[fi][fj], 0, 0, 0);
  }

  float xn[4];
#pragma unroll
  for (int fj = 0; fj < 4; ++fj)
    xn[fj] = norms32[(size_t)b * NN + m0 + wcol * 64 + fj * 16 + l15];

  // ---- pass 1: normal tile S[j-row][m-col] = xx[m] - 2g + 2048 ----
  __syncthreads();  // K-loop LDS reads done; reuse smem as 128 x SSTR fp16
#pragma unroll
  for (int fi = 0; fi < 4; ++fi)
#pragma unroll
    for (int fj = 0; fj < 4; ++fj)
#pragma unroll
      for (int r = 0; r < 4; ++r) {
        float sv = xn[fj] - 2.0f * acc[fi][fj][r] + 2048.0f;  // > 0 always
        smem[(wrow * 64 + fi * 16 + q * 4 + r) * SSTR + wcol * 64 + fj * 16 + l15] =
            __builtin_bit_cast(unsigned short, (_Float16)sv);
      }
  __syncthreads();
  sel_write(smem, Kws, b, j0, mt, m0, t);

  // ---- pass 2: mirror tile S[m-row][j-col] = xx[j] - 2g + 2048 ----
  if (jt != mt) {
    float xr[16];
#pragma unroll
    for (int fi = 0; fi < 4; ++fi)
#pragma unroll
      for (int r = 0; r < 4; ++r)
        xr[fi * 4 + r] =
            norms32[(size_t)b * NN + j0 + wrow * 64 + fi * 16 + q * 4 + r];

    __syncthreads();  // pass-1 selection reads done before overwrite
#pragma unroll
    for (int fi = 0; fi < 4; ++fi)
#pragma unroll
      for (int fj = 0; fj < 4; ++fj)
#pragma unroll
        for (int r = 0; r < 4; ++r) {
          float sv = xr[fi * 4 + r] - 2.0f * acc[fi][fj][r] + 2048.0f;
          smem[(wcol * 64 + fj * 16 + l15) * SSTR + wrow * 64 + fi * 16 + q * 4 + r] =
              __builtin_bit_cast(unsigned short, (_Float16)sv);
        }
    __syncthreads();
    sel_write(smem, Kws, b, m0, jt, j0, t);
  }
}

// ---------------------------------------------------------------------------
// Kernel 3: one wave per row.
//  P1: one coalesced uint4/lane (256 pre-filtered keys), sort4.
//  P2: 12 dual-extraction passes -> approx top-24 (validated structure).
//  P3: coalesced exact-fp64 rescore (validated).
//  P4: exact fp32 key chain + rank-count top-16 (validated).
//  P5: bitmask full-row coalesced write (validated).
// ---------------------------------------------------------------------------
__global__ __launch_bounds__(256) void knn_select(
    const unsigned* __restrict__ Kws,
    const float* __restrict__ put,
    const float* __restrict__ norms32,
    float* __restrict__ out) {
  __shared__ unsigned candL[4][NCAND];
  __shared__ double part[4][NCAND][9];
  __shared__ ull keyL[4][NCAND];
  __shared__ unsigned winL[4][16];

  const int wv   = threadIdx.x >> 6;
  const int lane = threadIdx.x & 63;
  const int R = blockIdx.x * 4 + wv;
  const int b = R >> 11, j = R & (NN - 1);

  // --- P1: 4 keys/lane, sorted ---
  uint4 kv = *(const uint4*)(Kws + ((size_t)R << 8) + lane * 4);
  unsigned h[4] = {kv.x, kv.y, kv.z, kv.w};
  CEX(h, 0, 1) CEX(h, 2, 3) CEX(h, 0, 2) CEX(h, 1, 3) CEX(h, 1, 2)

  // --- P2: 12 passes, two winners per pass ---
#pragma unroll
  for (int pass = 0; pass < NCAND / 2; ++pass) {
    unsigned a1 = h[0], a2 = h[1];
#pragma unroll
    for (int m = 1; m < 64; m <<= 1) {
      unsigned b1 = (unsigned)__shfl_xor((int)a1, m, 64);
      unsigned b2 = (unsigned)__shfl_xor((int)a2, m, 64);
      unsigned lo  = min(a1, b1);
      unsigned mid = max(a1, b1);
      unsigned hi  = min(a2, b2);
      a1 = lo;
      a2 = min(mid, hi);
    }
    if ((h[0] == a1) | (h[0] == a2)) {
      h[0] = h[1]; h[1] = h[2]; h[2] = h[3]; h[3] = 0xFFFFFFFFu;
    }
    if (h[0] == a2) {
      h[0] = h[1]; h[1] = h[2]; h[2] = h[3]; h[3] = 0xFFFFFFFFu;
    }
    if (lane == 0) {
      candL[wv][2 * pass]     = a1 & 0xFFFFu;
      candL[wv][2 * pass + 1] = a2 & 0xFFFFu;
    }
  }

  // --- P3: coalesced exact-fp64 rescore, 4 candidates in flight ---
  const float* panel = put + (size_t)b * NN * DD;
  const float* xjp = panel + (size_t)j * DD + lane * 8;
  float4 xa = ((const float4*)xjp)[0];
  float4 xb = ((const float4*)xjp)[1];
  double x0 = xa.x, x1 = xa.y, x2 = xa.z, x3 = xa.w;
  double x4 = xb.x, x5 = xb.y, x6 = xb.z, x7 = xb.w;

  for (int c0 = 0; c0 < NCAND; c0 += 4) {
    double p[4];
#pragma unroll
    for (int uu = 0; uu < 4; ++uu) {
      int cand = __builtin_amdgcn_readfirstlane((int)candL[wv][c0 + uu]);
      const float4* cr = (const float4*)(panel + (size_t)cand * DD + lane * 8);
      float4 ya = cr[0];
      float4 yb = cr[1];
      p[uu] = x0 * (double)ya.x + x1 * (double)ya.y + x2 * (double)ya.z +
              x3 * (double)ya.w + x4 * (double)yb.x + x5 * (double)yb.y +
              x6 * (double)yb.z + x7 * (double)yb.w;
    }
#pragma unroll
    for (int uu = 0; uu < 4; ++uu) {
      p[uu] += __shfl_xor(p[uu], 1, 64);
      p[uu] += __shfl_xor(p[uu], 2, 64);
      p[uu] += __shfl_xor(p[uu], 4, 64);
      if ((lane & 7) == 0) part[wv][c0 + uu][lane >> 3] = p[uu];
    }
  }

  // --- P4: exact keys + rank-count top-16 ---
  if (lane < NCAND) {
    double dot = part[wv][lane][0] + part[wv][lane][1] + part[wv][lane][2] +
                 part[wv][lane][3] + part[wv][lane][4] + part[wv][lane][5] +
                 part[wv][lane][6] + part[wv][lane][7];
    int cand = (int)candL[wv][lane];
    float g32 = (float)dot;
    float xxm = norms32[(size_t)b * NN + cand];
    float xxj = norms32[(size_t)b * NN + j];
    float s   = __fadd_rn(xxj, xxm);
    float d2  = __fsub_rn(s, __fmul_rn(2.0f, g32));
    d2 = fmaxf(d2, 0.0f);
    float dist = __fsqrt_rn(d2);
    keyL[wv][lane] = ((ull)__float_as_uint(dist) << 32) | (unsigned)cand;
  }
  if (lane < NCAND) {
    ull mine = keyL[wv][lane];
    int rank = 0;
#pragma unroll
    for (int i = 0; i < NCAND; ++i) rank += (keyL[wv][i] < mine) ? 1 : 0;
    if (rank < 16) winL[wv][rank] = (unsigned)(keyL[wv][lane] & 0xFFFFULL);
  }

  // --- P5: bitmask row build + full coalesced write ---
  unsigned mask = 0;
#pragma unroll
  for (int i = 0; i < 16; ++i) {
    unsigned c = winL[wv][i];
    unsigned own = (((c >> 2) & 63u) == (unsigned)lane) ? 1u : 0u;
    unsigned bit = (((c >> 8) & 7u) << 2) | (c & 3u);
    mask |= own << bit;
  }
  float* orow = out + (size_t)R * NN;
#pragma unroll
  for (int it = 0; it < 8; ++it) {
    float4 v;
    v.x = (float)((mask >> (it * 4 + 0)) & 1u);
    v.y = (float)((mask >> (it * 4 + 1)) & 1u);
    v.z = (float)((mask >> (it * 4 + 2)) & 1u);
    v.w = (float)((mask >> (it * 4 + 3)) & 1u);
    ((float4*)(orow + it * 256))[lane] = v;
  }
}

extern "C" void kernel_launch(void* const* d_in, const int* in_sizes, int n_in,
                              void* d_out, int out_size, void* d_ws, size_t ws_size,
                              hipStream_t stream) {
  const float* put = (const float*)d_in[0];
  // d_in[1] is k, fixed at 16 by setup_inputs(); hardcoded.
  float* out = (float*)d_out;

  float* norms32 = (float*)d_ws;                                  // 64 KB
  unsigned short* bhalf = (unsigned short*)((char*)d_ws + 65536); // 16.8 MB
  unsigned* Kws =
      (unsigned*)((char*)d_ws + 65536 + (size_t)NB * NN * DD * 2); // 16.8 MB

  knn_prep<<<dim3(NB * NN / 4), 256, 0, stream>>>(put, norms32, bhalf);
  knn_gemm<<<dim3(136, NB), 256, 0, stream>>>(bhalf, norms32, Kws);
  knn_select<<<dim3(NB * NN / 4), 256, 0, stream>>>(Kws, put, norms32, out);
}

// Round 11
// 250.768 us; speedup vs baseline: 1.0060x; 1.0060x over previous
//
#include <hip/hip_runtime.h>
#include <cstdint>

#define NN 2048
#define DD 512
#define NB 8
#define NCAND 24
#define SSTR 138  // LDS S-tile row stride (ushorts); 69 dwords, 5 mod 32 -> 2-way max

using ull = unsigned long long;
typedef __attribute__((ext_vector_type(8))) short bf16x8;
typedef __attribute__((ext_vector_type(4))) float f32x4;

// async global->LDS, 16 B per lane; LDS dest = wave-uniform base + lane*16
#define GLOAD_LDS16(g, l)                                                      \
  __builtin_amdgcn_global_load_lds(                                            \
      (const __attribute__((address_space(1))) unsigned int*)(g),              \
      (__attribute__((address_space(3))) unsigned int*)(l), 16, 0, 0)

// float -> bf16 RNE (no NaN in this data)
__device__ inline unsigned short f2bf(float f) {
  unsigned u = __float_as_uint(f);
  unsigned r = u + 0x7FFFu + ((u >> 16) & 1u);
  return (unsigned short)(r >> 16);
}

#define CEX(a, i, j)                                                           \
  {                                                                            \
    unsigned lo_ = min(a[i], a[j]), hi_ = max(a[i], a[j]);                     \
    a[i] = lo_;                                                                \
    a[j] = hi_;                                                                \
  }

__device__ __forceinline__ void sort8(unsigned (&a)[8]) {  // Batcher, 19 CE
  CEX(a, 0, 1) CEX(a, 2, 3) CEX(a, 4, 5) CEX(a, 6, 7)
  CEX(a, 0, 2) CEX(a, 1, 3) CEX(a, 4, 6) CEX(a, 5, 7)
  CEX(a, 1, 2) CEX(a, 5, 6)
  CEX(a, 0, 4) CEX(a, 1, 5) CEX(a, 2, 6) CEX(a, 3, 7)
  CEX(a, 2, 4) CEX(a, 3, 5)
  CEX(a, 1, 2) CEX(a, 3, 4) CEX(a, 5, 6)
}

// a, b sorted asc -> a = sorted 8 smallest of the 16
__device__ __forceinline__ void merge8(unsigned (&a)[8], const unsigned (&b)[8]) {
  unsigned t[8];
#pragma unroll
  for (int i = 0; i < 8; ++i) t[i] = min(a[i], b[7 - i]);  // bitonic
  CEX(t, 0, 4) CEX(t, 1, 5) CEX(t, 2, 6) CEX(t, 3, 7)
  CEX(t, 0, 2) CEX(t, 1, 3) CEX(t, 4, 6) CEX(t, 5, 7)
  CEX(t, 0, 1) CEX(t, 2, 3) CEX(t, 4, 5) CEX(t, 6, 7)
#pragma unroll
  for (int i = 0; i < 8; ++i) a[i] = t[i];
}

__device__ __forceinline__ void load8(unsigned (&a)[8], const unsigned short* p,
                                      unsigned c0) {
  uint4 u = *(const uint4*)p;
  a[0] = (u.x << 16) | c0;
  a[1] = (u.x & 0xFFFF0000u) | (c0 + 1);
  a[2] = (u.y << 16) | (c0 + 2);
  a[3] = (u.y & 0xFFFF0000u) | (c0 + 3);
  a[4] = (u.z << 16) | (c0 + 4);
  a[5] = (u.z & 0xFFFF0000u) | (c0 + 5);
  a[6] = (u.w << 16) | (c0 + 6);
  a[7] = (u.w & 0xFFFF0000u) | (c0 + 7);
}

// Per-half-row exact top-8 of a 64-col S half-tile in LDS (stride SSTR).
// Thread t: row = t>>1, half = t&1. Streaming sort8 + merge8 (no shfl).
// Keys = (fp16bits << 16) | global_col (monotone, lower-index tie).
// Kws layout: [row][tile][half][8] -> 256 keys/row, coalesced uint4 in select.
__device__ __forceinline__ void sel_write(const unsigned short* S,
                                          unsigned* __restrict__ Kws, int b,
                                          int rowbase, int tile, int colbase,
                                          int t) {
  const int row = t >> 1, half = t & 1;
  const unsigned short* Sr = S + row * SSTR + half * 64;
  const unsigned cb = (unsigned)(colbase + half * 64);
  unsigned m[8], s1[8];
  load8(m, Sr, cb);
  sort8(m);
#pragma unroll
  for (int c = 8; c < 64; c += 8) {
    load8(s1, Sr + c, cb + c);
    sort8(s1);
    merge8(m, s1);
  }
  unsigned* dst =
      Kws + (((size_t)(b * NN + rowbase + row) * 16 + tile) << 4) + half * 8;
  uint4 v0, v1;
  v0.x = m[0]; v0.y = m[1]; v0.z = m[2]; v0.w = m[3];
  v1.x = m[4]; v1.y = m[5]; v1.z = m[6]; v1.w = m[7];
  ((uint4*)dst)[0] = v0;
  ((uint4*)dst)[1] = v1;
}

// ---------------------------------------------------------------------------
// Kernel 1: per-row fp32 norm (exact fp64 sum — validated chain) + bf16 copy.
// ---------------------------------------------------------------------------
__global__ __launch_bounds__(256) void knn_prep(const float* __restrict__ put,
                                                float* __restrict__ norms32,
                                                unsigned short* __restrict__ bhalf) {
  const int row  = blockIdx.x * 4 + (threadIdx.x >> 6);
  const int lane = threadIdx.x & 63;
  const float* p = put + (size_t)row * DD + lane * 8;
  float4 x0 = ((const float4*)p)[0];
  float4 x1 = ((const float4*)p)[1];
  double s = (double)x0.x * (double)x0.x + (double)x0.y * (double)x0.y +
             (double)x0.z * (double)x0.z + (double)x0.w * (double)x0.w +
             (double)x1.x * (double)x1.x + (double)x1.y * (double)x1.y +
             (double)x1.z * (double)x1.z + (double)x1.w * (double)x1.w;
  uint4 v;
  v.x = (unsigned)f2bf(x0.x) | ((unsigned)f2bf(x0.y) << 16);
  v.y = (unsigned)f2bf(x0.z) | ((unsigned)f2bf(x0.w) << 16);
  v.z = (unsigned)f2bf(x1.x) | ((unsigned)f2bf(x1.y) << 16);
  v.w = (unsigned)f2bf(x1.z) | ((unsigned)f2bf(x1.w) << 16);
  *((uint4*)(bhalf + (size_t)row * DD) + lane) = v;
#pragma unroll
  for (int m = 1; m < 64; m <<= 1) s += __shfl_xor(s, m, 64);
  if (lane == 0) norms32[row] = (float)s;
}

// ---------------------------------------------------------------------------
// Kernel 2: symmetric bf16 MFMA Gram + fused per-half-row top-8 key epilogue.
// XCD-affine 1-D grid: batch = blockIdx.x & 7 (workgroups round-robin across
// the 8 XCDs -> each XCD's L2 touches only its batch's 2 MB bf16 panel).
// S never hits HBM. K-loop: validated m97-style global_load_lds + XOR swizzle.
// ---------------------------------------------------------------------------
__global__ __launch_bounds__(256) void knn_gemm(
    const unsigned short* __restrict__ bhalf,
    const float* __restrict__ norms32,
    unsigned* __restrict__ Kws) {
  __shared__ unsigned short smem[17664];  // 35328 B; K-loop: As/Bs; epi: S
  unsigned short* As = smem;              // 8 KB: 128 rows x 32 ushorts
  unsigned short* Bs = smem + 4096;       // 8 KB

  const int b = blockIdx.x & 7;       // XCD-affine batch
  int idx = blockIdx.x >> 3;          // triangle tile index 0..135
  int jt = 0;
  while (idx >= 16 - jt) { idx -= 16 - jt; ++jt; }
  const int mt = jt + idx;

  const int t    = threadIdx.x;
  const int lane = t & 63;
  const int wv   = t >> 6;
  const int q    = lane >> 4;
  const int l15  = lane & 15;
  const int wrow = wv >> 1, wcol = wv & 1;
  const int m0 = mt * 128;
  const int j0 = jt * 128;

  const unsigned short* pb = bhalf + (size_t)b * NN * DD;

  const int rloc = lane >> 2;
  const int kcg  = (lane & 3) ^ ((lane >> 3) & 3);
  const int i0 = 2 * wv, i1 = 2 * wv + 1;
  const unsigned short* gA0 = pb + (size_t)(j0 + 16 * i0 + rloc) * DD + kcg * 8;
  const unsigned short* gA1 = pb + (size_t)(j0 + 16 * i1 + rloc) * DD + kcg * 8;
  const unsigned short* gB0 = pb + (size_t)(m0 + 16 * i0 + rloc) * DD + kcg * 8;
  const unsigned short* gB1 = pb + (size_t)(m0 + 16 * i1 + rloc) * DD + kcg * 8;
  unsigned short* lA0 = As + i0 * 512;
  unsigned short* lA1 = As + i1 * 512;
  unsigned short* lB0 = Bs + i0 * 512;
  unsigned short* lB1 = Bs + i1 * 512;

  const int xsw = (q ^ ((l15 >> 1) & 3)) * 8;  // ushort offset

  f32x4 acc[4][4];
  const f32x4 zz = {0.f, 0.f, 0.f, 0.f};
#pragma unroll
  for (int i = 0; i < 4; ++i)
#pragma unroll
    for (int j = 0; j < 4; ++j) acc[i][j] = zz;

  for (int kt = 0; kt < DD; kt += 32) {
    __syncthreads();
    GLOAD_LDS16(gA0, lA0);
    GLOAD_LDS16(gA1, lA1);
    GLOAD_LDS16(gB0, lB0);
    GLOAD_LDS16(gB1, lB1);
    gA0 += 32; gA1 += 32; gB0 += 32; gB1 += 32;
    __syncthreads();

    bf16x8 af[4], bg[4];
#pragma unroll
    for (int f = 0; f < 4; ++f) {
      af[f] = *(const bf16x8*)(As + (wrow * 64 + f * 16 + l15) * 32 + xsw);
      bg[f] = *(const bf16x8*)(Bs + (wcol * 64 + f * 16 + l15) * 32 + xsw);
    }
#pragma unroll
    for (int fi = 0; fi < 4; ++fi)
#pragma unroll
      for (int fj = 0; fj < 4; ++fj)
        acc[fi][fj] = __builtin_amdgcn_mfma_f32_16x16x32_bf16(
            af[fi], bg[fj], acc[fi][fj], 0, 0, 0);
  }

  float xn[4];
#pragma unroll
  for (int fj = 0; fj < 4; ++fj)
    xn[fj] = norms32[(size_t)b * NN + m0 + wcol * 64 + fj * 16 + l15];

  // ---- pass 1: normal tile S[j-row][m-col] = xx[m] - 2g + 2048 ----
  __syncthreads();  // K-loop LDS reads done; reuse smem as 128 x SSTR fp16
#pragma unroll
  for (int fi = 0; fi < 4; ++fi)
#pragma unroll
    for (int fj = 0; fj < 4; ++fj)
#pragma unroll
      for (int r = 0; r < 4; ++r) {
        float sv = xn[fj] - 2.0f * acc[fi][fj][r] + 2048.0f;  // > 0 always
        smem[(wrow * 64 + fi * 16 + q * 4 + r) * SSTR + wcol * 64 + fj * 16 + l15] =
            __builtin_bit_cast(unsigned short, (_Float16)sv);
      }
  __syncthreads();
  sel_write(smem, Kws, b, j0, mt, m0, t);

  // ---- pass 2: mirror tile S[m-row][j-col] = xx[j] - 2g + 2048 ----
  if (jt != mt) {
    float xr[16];
#pragma unroll
    for (int fi = 0; fi < 4; ++fi)
#pragma unroll
      for (int r = 0; r < 4; ++r)
        xr[fi * 4 + r] =
            norms32[(size_t)b * NN + j0 + wrow * 64 + fi * 16 + q * 4 + r];

    __syncthreads();  // pass-1 selection reads done before overwrite
#pragma unroll
    for (int fi = 0; fi < 4; ++fi)
#pragma unroll
      for (int fj = 0; fj < 4; ++fj)
#pragma unroll
        for (int r = 0; r < 4; ++r) {
          float sv = xr[fi * 4 + r] - 2.0f * acc[fi][fj][r] + 2048.0f;
          smem[(wcol * 64 + fj * 16 + l15) * SSTR + wrow * 64 + fi * 16 + q * 4 + r] =
              __builtin_bit_cast(unsigned short, (_Float16)sv);
        }
    __syncthreads();
    sel_write(smem, Kws, b, m0, jt, j0, t);
  }
}

// ---------------------------------------------------------------------------
// Kernel 3: one wave per row. XCD-affine 1-D grid: batch = blockIdx.x & 7,
// so each XCD's L2 holds only its batch's 4 MB fp32 panel for the rescore
// gather. Out stores are non-temporal (never re-read; don't evict panels).
//  P1: one coalesced uint4/lane (256 pre-filtered keys), sort4.
//  P2: 12 dual-extraction passes -> approx top-24 (validated structure).
//  P3: coalesced exact-fp64 rescore (validated).
//  P4: exact fp32 key chain + rank-count top-16 (validated).
//  P5: bitmask full-row nontemporal write.
// ---------------------------------------------------------------------------
__global__ __launch_bounds__(256) void knn_select(
    const unsigned* __restrict__ Kws,
    const float* __restrict__ put,
    const float* __restrict__ norms32,
    float* __restrict__ out) {
  __shared__ unsigned candL[4][NCAND];
  __shared__ double part[4][NCAND][9];
  __shared__ ull keyL[4][NCAND];
  __shared__ unsigned winL[4][16];

  const int wv   = threadIdx.x >> 6;
  const int lane = threadIdx.x & 63;
  const int b  = blockIdx.x & 7;                  // XCD-affine batch
  const int j  = (blockIdx.x >> 3) * 4 + wv;      // row within batch
  const int R  = b * NN + j;

  // --- P1: 4 keys/lane, sorted ---
  uint4 kv = *(const uint4*)(Kws + ((size_t)R << 8) + lane * 4);
  unsigned h[4] = {kv.x, kv.y, kv.z, kv.w};
  CEX(h, 0, 1) CEX(h, 2, 3) CEX(h, 0, 2) CEX(h, 1, 3) CEX(h, 1, 2)

  // --- P2: 12 passes, two winners per pass ---
#pragma unroll
  for (int pass = 0; pass < NCAND / 2; ++pass) {
    unsigned a1 = h[0], a2 = h[1];
#pragma unroll
    for (int m = 1; m < 64; m <<= 1) {
      unsigned b1 = (unsigned)__shfl_xor((int)a1, m, 64);
      unsigned b2 = (unsigned)__shfl_xor((int)a2, m, 64);
      unsigned lo  = min(a1, b1);
      unsigned mid = max(a1, b1);
      unsigned hi  = min(a2, b2);
      a1 = lo;
      a2 = min(mid, hi);
    }
    if ((h[0] == a1) | (h[0] == a2)) {
      h[0] = h[1]; h[1] = h[2]; h[2] = h[3]; h[3] = 0xFFFFFFFFu;
    }
    if (h[0] == a2) {
      h[0] = h[1]; h[1] = h[2]; h[2] = h[3]; h[3] = 0xFFFFFFFFu;
    }
    if (lane == 0) {
      candL[wv][2 * pass]     = a1 & 0xFFFFu;
      candL[wv][2 * pass + 1] = a2 & 0xFFFFu;
    }
  }

  // --- P3: coalesced exact-fp64 rescore, 4 candidates in flight ---
  const float* panel = put + (size_t)b * NN * DD;
  const float* xjp = panel + (size_t)j * DD + lane * 8;
  float4 xa = ((const float4*)xjp)[0];
  float4 xb = ((const float4*)xjp)[1];
  double x0 = xa.x, x1 = xa.y, x2 = xa.z, x3 = xa.w;
  double x4 = xb.x, x5 = xb.y, x6 = xb.z, x7 = xb.w;

  for (int c0 = 0; c0 < NCAND; c0 += 4) {
    double p[4];
#pragma unroll
    for (int uu = 0; uu < 4; ++uu) {
      int cand = __builtin_amdgcn_readfirstlane((int)candL[wv][c0 + uu]);
      const float4* cr = (const float4*)(panel + (size_t)cand * DD + lane * 8);
      float4 ya = cr[0];
      float4 yb = cr[1];
      p[uu] = x0 * (double)ya.x + x1 * (double)ya.y + x2 * (double)ya.z +
              x3 * (double)ya.w + x4 * (double)yb.x + x5 * (double)yb.y +
              x6 * (double)yb.z + x7 * (double)yb.w;
    }
#pragma unroll
    for (int uu = 0; uu < 4; ++uu) {
      p[uu] += __shfl_xor(p[uu], 1, 64);
      p[uu] += __shfl_xor(p[uu], 2, 64);
      p[uu] += __shfl_xor(p[uu], 4, 64);
      if ((lane & 7) == 0) part[wv][c0 + uu][lane >> 3] = p[uu];
    }
  }

  // --- P4: exact keys + rank-count top-16 ---
  if (lane < NCAND) {
    double dot = part[wv][lane][0] + part[wv][lane][1] + part[wv][lane][2] +
                 part[wv][lane][3] + part[wv][lane][4] + part[wv][lane][5] +
                 part[wv][lane][6] + part[wv][lane][7];
    int cand = (int)candL[wv][lane];
    float g32 = (float)dot;
    float xxm = norms32[(size_t)b * NN + cand];
    float xxj = norms32[(size_t)b * NN + j];
    float s   = __fadd_rn(xxj, xxm);
    float d2  = __fsub_rn(s, __fmul_rn(2.0f, g32));
    d2 = fmaxf(d2, 0.0f);
    float dist = __fsqrt_rn(d2);
    keyL[wv][lane] = ((ull)__float_as_uint(dist) << 32) | (unsigned)cand;
  }
  if (lane < NCAND) {
    ull mine = keyL[wv][lane];
    int rank = 0;
#pragma unroll
    for (int i = 0; i < NCAND; ++i) rank += (keyL[wv][i] < mine) ? 1 : 0;
    if (rank < 16) winL[wv][rank] = (unsigned)(keyL[wv][lane] & 0xFFFFULL);
  }

  // --- P5: bitmask row build + full nontemporal coalesced write ---
  unsigned mask = 0;
#pragma unroll
  for (int i = 0; i < 16; ++i) {
    unsigned c = winL[wv][i];
    unsigned own = (((c >> 2) & 63u) == (unsigned)lane) ? 1u : 0u;
    unsigned bit = (((c >> 8) & 7u) << 2) | (c & 3u);
    mask |= own << bit;
  }
  float* orow = out + (size_t)R * NN;
#pragma unroll
  for (int it = 0; it < 8; ++it) {
    f32x4 v;
    v[0] = (float)((mask >> (it * 4 + 0)) & 1u);
    v[1] = (float)((mask >> (it * 4 + 1)) & 1u);
    v[2] = (float)((mask >> (it * 4 + 2)) & 1u);
    v[3] = (float)((mask >> (it * 4 + 3)) & 1u);
    __builtin_nontemporal_store(v, (f32x4*)(orow + it * 256) + lane);
  }
}

extern "C" void kernel_launch(void* const* d_in, const int* in_sizes, int n_in,
                              void* d_out, int out_size, void* d_ws, size_t ws_size,
                              hipStream_t stream) {
  const float* put = (const float*)d_in[0];
  // d_in[1] is k, fixed at 16 by setup_inputs(); hardcoded.
  float* out = (float*)d_out;

  float* norms32 = (float*)d_ws;                                  // 64 KB
  unsigned short* bhalf = (unsigned short*)((char*)d_ws + 65536); // 16.8 MB
  unsigned* Kws =
      (unsigned*)((char*)d_ws + 65536 + (size_t)NB * NN * DD * 2); // 16.8 MB

  knn_prep<<<dim3(NB * NN / 4), 256, 0, stream>>>(put, norms32, bhalf);
  knn_gemm<<<dim3(136 * NB), 256, 0, stream>>>(bhalf, norms32, Kws);
  knn_select<<<dim3((NN / 4) * NB), 256, 0, stream>>>(Kws, put, norms32, out);
}

// Round 12
// 245.583 us; speedup vs baseline: 1.0272x; 1.0211x over previous
//
#include <hip/hip_runtime.h>
#include <cstdint>

#define NN 2048
#define DD 512
#define NB 8
#define NCAND 24
#define SSTR 138  // LDS S-tile row stride (ushorts); 69 dwords, 5 mod 32 -> 2-way max

using ull = unsigned long long;
typedef __attribute__((ext_vector_type(8))) short bf16x8;
typedef __attribute__((ext_vector_type(4))) float f32x4;

// async global->LDS, 16 B per lane; LDS dest = wave-uniform base + lane*16
#define GLOAD_LDS16(g, l)                                                      \
  __builtin_amdgcn_global_load_lds(                                            \
      (const __attribute__((address_space(1))) unsigned int*)(g),              \
      (__attribute__((address_space(3))) unsigned int*)(l), 16, 0, 0)

// float -> bf16 RNE (no NaN in this data)
__device__ inline unsigned short f2bf(float f) {
  unsigned u = __float_as_uint(f);
  unsigned r = u + 0x7FFFu + ((u >> 16) & 1u);
  return (unsigned short)(r >> 16);
}

#define CEX(a, i, j)                                                           \
  {                                                                            \
    unsigned lo_ = min(a[i], a[j]), hi_ = max(a[i], a[j]);                     \
    a[i] = lo_;                                                                \
    a[j] = hi_;                                                                \
  }

__device__ __forceinline__ void sort8(unsigned (&a)[8]) {  // Batcher, 19 CE
  CEX(a, 0, 1) CEX(a, 2, 3) CEX(a, 4, 5) CEX(a, 6, 7)
  CEX(a, 0, 2) CEX(a, 1, 3) CEX(a, 4, 6) CEX(a, 5, 7)
  CEX(a, 1, 2) CEX(a, 5, 6)
  CEX(a, 0, 4) CEX(a, 1, 5) CEX(a, 2, 6) CEX(a, 3, 7)
  CEX(a, 2, 4) CEX(a, 3, 5)
  CEX(a, 1, 2) CEX(a, 3, 4) CEX(a, 5, 6)
}

// a, b sorted asc -> a = sorted 8 smallest of the 16
__device__ __forceinline__ void merge8(unsigned (&a)[8], const unsigned (&b)[8]) {
  unsigned t[8];
#pragma unroll
  for (int i = 0; i < 8; ++i) t[i] = min(a[i], b[7 - i]);  // bitonic
  CEX(t, 0, 4) CEX(t, 1, 5) CEX(t, 2, 6) CEX(t, 3, 7)
  CEX(t, 0, 2) CEX(t, 1, 3) CEX(t, 4, 6) CEX(t, 5, 7)
  CEX(t, 0, 1) CEX(t, 2, 3) CEX(t, 4, 5) CEX(t, 6, 7)
#pragma unroll
  for (int i = 0; i < 8; ++i) a[i] = t[i];
}

__device__ __forceinline__ void load8(unsigned (&a)[8], const unsigned short* p,
                                      unsigned c0) {
  uint4 u = *(const uint4*)p;
  a[0] = (u.x << 16) | c0;
  a[1] = (u.x & 0xFFFF0000u) | (c0 + 1);
  a[2] = (u.y << 16) | (c0 + 2);
  a[3] = (u.y & 0xFFFF0000u) | (c0 + 3);
  a[4] = (u.z << 16) | (c0 + 4);
  a[5] = (u.z & 0xFFFF0000u) | (c0 + 5);
  a[6] = (u.w << 16) | (c0 + 6);
  a[7] = (u.w & 0xFFFF0000u) | (c0 + 7);
}

// Per-half-row exact top-8 of a 64-col S half-tile in LDS (stride SSTR).
__device__ __forceinline__ void sel_write(const unsigned short* S,
                                          unsigned* __restrict__ Kws, int b,
                                          int rowbase, int tile, int colbase,
                                          int t) {
  const int row = t >> 1, half = t & 1;
  const unsigned short* Sr = S + row * SSTR + half * 64;
  const unsigned cb = (unsigned)(colbase + half * 64);
  unsigned m[8], s1[8];
  load8(m, Sr, cb);
  sort8(m);
#pragma unroll
  for (int c = 8; c < 64; c += 8) {
    load8(s1, Sr + c, cb + c);
    sort8(s1);
    merge8(m, s1);
  }
  unsigned* dst =
      Kws + (((size_t)(b * NN + rowbase + row) * 16 + tile) << 4) + half * 8;
  uint4 v0, v1;
  v0.x = m[0]; v0.y = m[1]; v0.z = m[2]; v0.w = m[3];
  v1.x = m[4]; v1.y = m[5]; v1.z = m[6]; v1.w = m[7];
  ((uint4*)dst)[0] = v0;
  ((uint4*)dst)[1] = v1;
}

// ---------------------------------------------------------------------------
// Kernel 1: per-row fp32 norm (exact fp64 sum — validated chain) + bf16 copy.
// ---------------------------------------------------------------------------
__global__ __launch_bounds__(256) void knn_prep(const float* __restrict__ put,
                                                float* __restrict__ norms32,
                                                unsigned short* __restrict__ bhalf) {
  const int row  = blockIdx.x * 4 + (threadIdx.x >> 6);
  const int lane = threadIdx.x & 63;
  const float* p = put + (size_t)row * DD + lane * 8;
  float4 x0 = ((const float4*)p)[0];
  float4 x1 = ((const float4*)p)[1];
  double s = (double)x0.x * (double)x0.x + (double)x0.y * (double)x0.y +
             (double)x0.z * (double)x0.z + (double)x0.w * (double)x0.w +
             (double)x1.x * (double)x1.x + (double)x1.y * (double)x1.y +
             (double)x1.z * (double)x1.z + (double)x1.w * (double)x1.w;
  uint4 v;
  v.x = (unsigned)f2bf(x0.x) | ((unsigned)f2bf(x0.y) << 16);
  v.y = (unsigned)f2bf(x0.z) | ((unsigned)f2bf(x0.w) << 16);
  v.z = (unsigned)f2bf(x1.x) | ((unsigned)f2bf(x1.y) << 16);
  v.w = (unsigned)f2bf(x1.z) | ((unsigned)f2bf(x1.w) << 16);
  *((uint4*)(bhalf + (size_t)row * DD) + lane) = v;
#pragma unroll
  for (int m = 1; m < 64; m <<= 1) s += __shfl_xor(s, m, 64);
  if (lane == 0) norms32[row] = (float)s;
}

// ---------------------------------------------------------------------------
// Kernel 2: symmetric bf16 MFMA Gram + fused per-half-row top-8 key epilogue.
// BK=64 K-loop: 8 iterations (vs 16), 32 MFMA per barrier pair — halves the
// vmcnt(0)+s_barrier drain count that pins the m97 structure at ~320 TF for
// this shape. Staging: lane-linear global_load_lds, 8-chunk XOR swizzle
// (g = (l&7) ^ (row&7); fragment reads land 2 lanes/bank = free).
// XCD-affine 1-D grid: batch = blockIdx.x & 7. S never hits HBM.
// ---------------------------------------------------------------------------
__global__ __launch_bounds__(256) void knn_gemm(
    const unsigned short* __restrict__ bhalf,
    const float* __restrict__ norms32,
    unsigned* __restrict__ Kws) {
  __shared__ unsigned short smem[17664];  // 35328 B; K-loop: As/Bs; epi: S
  unsigned short* As = smem;              // 16 KB: 128 rows x 64 ushorts
  unsigned short* Bs = smem + 8192;       // 16 KB

  const int b = blockIdx.x & 7;       // XCD-affine batch
  int idx = blockIdx.x >> 3;          // triangle tile index 0..135
  int jt = 0;
  while (idx >= 16 - jt) { idx -= 16 - jt; ++jt; }
  const int mt = jt + idx;

  const int t    = threadIdx.x;
  const int lane = t & 63;
  const int wv   = t >> 6;
  const int q    = lane >> 4;
  const int l15  = lane & 15;
  const int wrow = wv >> 1, wcol = wv & 1;
  const int m0 = mt * 128;
  const int j0 = jt * 128;

  const unsigned short* pb = bhalf + (size_t)b * NN * DD;

  // staging: 32 blocks of 8 rows (16 per matrix); wave wv owns A/B blocks
  // ib = 4wv..4wv+3. lane l -> row 8*ib + (l>>3), chunk pos p = l&7 holds
  // global chunk g = p ^ (row&7)  (inverse of the fragment read swizzle).
  const int rl  = lane >> 3;             // row within 8-row block
  const int gch = (lane & 7) ^ (rl & 7); // global 16B chunk index 0..7
  const unsigned short* gA[4];
  const unsigned short* gB[4];
  unsigned short* lA[4];
  unsigned short* lB[4];
#pragma unroll
  for (int i = 0; i < 4; ++i) {
    const int ib = wv * 4 + i;
    gA[i] = pb + (size_t)(j0 + 8 * ib + rl) * DD + gch * 8;
    gB[i] = pb + (size_t)(m0 + 8 * ib + rl) * DD + gch * 8;
    lA[i] = As + ib * 512;  // wave-uniform (8 rows x 64 ushorts = 512)
    lB[i] = Bs + ib * 512;
  }

  f32x4 acc[4][4];
  const f32x4 zz = {0.f, 0.f, 0.f, 0.f};
#pragma unroll
  for (int i = 0; i < 4; ++i)
#pragma unroll
    for (int j = 0; j < 4; ++j) acc[i][j] = zz;

  // fragment read: row r, k-step s, quad q -> chunk g = s*4+q at pos g^(r&7)
  const int r7a = l15 & 7;  // (wrow*64 + f*16 + l15) & 7 == l15 & 7

  for (int kt = 0; kt < DD; kt += 64) {
    __syncthreads();  // prior iteration's ds_reads complete
#pragma unroll
    for (int i = 0; i < 4; ++i) {
      GLOAD_LDS16(gA[i], lA[i]);
      GLOAD_LDS16(gB[i], lB[i]);
      gA[i] += 64;
      gB[i] += 64;
    }
    __syncthreads();  // vmcnt(0) drain + barrier: LDS tile ready

#pragma unroll
    for (int s = 0; s < 2; ++s) {
      bf16x8 af[4], bg[4];
#pragma unroll
      for (int f = 0; f < 4; ++f) {
        const int pa = ((s * 4 + q) ^ r7a) * 8;
        af[f] = *(const bf16x8*)(As + (wrow * 64 + f * 16 + l15) * 64 + pa);
        bg[f] = *(const bf16x8*)(Bs + (wcol * 64 + f * 16 + l15) * 64 + pa);
      }
#pragma unroll
      for (int fi = 0; fi < 4; ++fi)
#pragma unroll
        for (int fj = 0; fj < 4; ++fj)
          acc[fi][fj] = __builtin_amdgcn_mfma_f32_16x16x32_bf16(
              af[fi], bg[fj], acc[fi][fj], 0, 0, 0);
    }
  }

  float xn[4];
#pragma unroll
  for (int fj = 0; fj < 4; ++fj)
    xn[fj] = norms32[(size_t)b * NN + m0 + wcol * 64 + fj * 16 + l15];

  // ---- pass 1: normal tile S[j-row][m-col] = xx[m] - 2g + 2048 ----
  __syncthreads();  // K-loop LDS reads done; reuse smem as 128 x SSTR fp16
#pragma unroll
  for (int fi = 0; fi < 4; ++fi)
#pragma unroll
    for (int fj = 0; fj < 4; ++fj)
#pragma unroll
      for (int r = 0; r < 4; ++r) {
        float sv = xn[fj] - 2.0f * acc[fi][fj][r] + 2048.0f;  // > 0 always
        smem[(wrow * 64 + fi * 16 + q * 4 + r) * SSTR + wcol * 64 + fj * 16 + l15] =
            __builtin_bit_cast(unsigned short, (_Float16)sv);
      }
  __syncthreads();
  sel_write(smem, Kws, b, j0, mt, m0, t);

  // ---- pass 2: mirror tile S[m-row][j-col] = xx[j] - 2g + 2048 ----
  if (jt != mt) {
    float xr[16];
#pragma unroll
    for (int fi = 0; fi < 4; ++fi)
#pragma unroll
      for (int r = 0; r < 4; ++r)
        xr[fi * 4 + r] =
            norms32[(size_t)b * NN + j0 + wrow * 64 + fi * 16 + q * 4 + r];

    __syncthreads();  // pass-1 selection reads done before overwrite
#pragma unroll
    for (int fi = 0; fi < 4; ++fi)
#pragma unroll
      for (int fj = 0; fj < 4; ++fj)
#pragma unroll
        for (int r = 0; r < 4; ++r) {
          float sv = xr[fi * 4 + r] - 2.0f * acc[fi][fj][r] + 2048.0f;
          smem[(wcol * 64 + fj * 16 + l15) * SSTR + wrow * 64 + fi * 16 + q * 4 + r] =
              __builtin_bit_cast(unsigned short, (_Float16)sv);
        }
    __syncthreads();
    sel_write(smem, Kws, b, m0, jt, j0, t);
  }
}

// ---------------------------------------------------------------------------
// Kernel 3: one wave per row (unchanged from round 11 — validated).
// XCD-affine grid, nontemporal out stores.
// ---------------------------------------------------------------------------
__global__ __launch_bounds__(256) void knn_select(
    const unsigned* __restrict__ Kws,
    const float* __restrict__ put,
    const float* __restrict__ norms32,
    float* __restrict__ out) {
  __shared__ unsigned candL[4][NCAND];
  __shared__ double part[4][NCAND][9];
  __shared__ ull keyL[4][NCAND];
  __shared__ unsigned winL[4][16];

  const int wv   = threadIdx.x >> 6;
  const int lane = threadIdx.x & 63;
  const int b  = blockIdx.x & 7;                  // XCD-affine batch
  const int j  = (blockIdx.x >> 3) * 4 + wv;      // row within batch
  const int R  = b * NN + j;

  // --- P1: 4 keys/lane, sorted ---
  uint4 kv = *(const uint4*)(Kws + ((size_t)R << 8) + lane * 4);
  unsigned h[4] = {kv.x, kv.y, kv.z, kv.w};
  CEX(h, 0, 1) CEX(h, 2, 3) CEX(h, 0, 2) CEX(h, 1, 3) CEX(h, 1, 2)

  // --- P2: 12 passes, two winners per pass ---
#pragma unroll
  for (int pass = 0; pass < NCAND / 2; ++pass) {
    unsigned a1 = h[0], a2 = h[1];
#pragma unroll
    for (int m = 1; m < 64; m <<= 1) {
      unsigned b1 = (unsigned)__shfl_xor((int)a1, m, 64);
      unsigned b2 = (unsigned)__shfl_xor((int)a2, m, 64);
      unsigned lo  = min(a1, b1);
      unsigned mid = max(a1, b1);
      unsigned hi  = min(a2, b2);
      a1 = lo;
      a2 = min(mid, hi);
    }
    if ((h[0] == a1) | (h[0] == a2)) {
      h[0] = h[1]; h[1] = h[2]; h[2] = h[3]; h[3] = 0xFFFFFFFFu;
    }
    if (h[0] == a2) {
      h[0] = h[1]; h[1] = h[2]; h[2] = h[3]; h[3] = 0xFFFFFFFFu;
    }
    if (lane == 0) {
      candL[wv][2 * pass]     = a1 & 0xFFFFu;
      candL[wv][2 * pass + 1] = a2 & 0xFFFFu;
    }
  }

  // --- P3: coalesced exact-fp64 rescore, 4 candidates in flight ---
  const float* panel = put + (size_t)b * NN * DD;
  const float* xjp = panel + (size_t)j * DD + lane * 8;
  float4 xa = ((const float4*)xjp)[0];
  float4 xb = ((const float4*)xjp)[1];
  double x0 = xa.x, x1 = xa.y, x2 = xa.z, x3 = xa.w;
  double x4 = xb.x, x5 = xb.y, x6 = xb.z, x7 = xb.w;

  for (int c0 = 0; c0 < NCAND; c0 += 4) {
    double p[4];
#pragma unroll
    for (int uu = 0; uu < 4; ++uu) {
      int cand = __builtin_amdgcn_readfirstlane((int)candL[wv][c0 + uu]);
      const float4* cr = (const float4*)(panel + (size_t)cand * DD + lane * 8);
      float4 ya = cr[0];
      float4 yb = cr[1];
      p[uu] = x0 * (double)ya.x + x1 * (double)ya.y + x2 * (double)ya.z +
              x3 * (double)ya.w + x4 * (double)yb.x + x5 * (double)yb.y +
              x6 * (double)yb.z + x7 * (double)yb.w;
    }
#pragma unroll
    for (int uu = 0; uu < 4; ++uu) {
      p[uu] += __shfl_xor(p[uu], 1, 64);
      p[uu] += __shfl_xor(p[uu], 2, 64);
      p[uu] += __shfl_xor(p[uu], 4, 64);
      if ((lane & 7) == 0) part[wv][c0 + uu][lane >> 3] = p[uu];
    }
  }

  // --- P4: exact keys + rank-count top-16 ---
  if (lane < NCAND) {
    double dot = part[wv][lane][0] + part[wv][lane][1] + part[wv][lane][2] +
                 part[wv][lane][3] + part[wv][lane][4] + part[wv][lane][5] +
                 part[wv][lane][6] + part[wv][lane][7];
    int cand = (int)candL[wv][lane];
    float g32 = (float)dot;
    float xxm = norms32[(size_t)b * NN + cand];
    float xxj = norms32[(size_t)b * NN + j];
    float s   = __fadd_rn(xxj, xxm);
    float d2  = __fsub_rn(s, __fmul_rn(2.0f, g32));
    d2 = fmaxf(d2, 0.0f);
    float dist = __fsqrt_rn(d2);
    keyL[wv][lane] = ((ull)__float_as_uint(dist) << 32) | (unsigned)cand;
  }
  if (lane < NCAND) {
    ull mine = keyL[wv][lane];
    int rank = 0;
#pragma unroll
    for (int i = 0; i < NCAND; ++i) rank += (keyL[wv][i] < mine) ? 1 : 0;
    if (rank < 16) winL[wv][rank] = (unsigned)(keyL[wv][lane] & 0xFFFFULL);
  }

  // --- P5: bitmask row build + full nontemporal coalesced write ---
  unsigned mask = 0;
#pragma unroll
  for (int i = 0; i < 16; ++i) {
    unsigned c = winL[wv][i];
    unsigned own = (((c >> 2) & 63u) == (unsigned)lane) ? 1u : 0u;
    unsigned bit = (((c >> 8) & 7u) << 2) | (c & 3u);
    mask |= own << bit;
  }
  float* orow = out + (size_t)R * NN;
#pragma unroll
  for (int it = 0; it < 8; ++it) {
    f32x4 v;
    v[0] = (float)((mask >> (it * 4 + 0)) & 1u);
    v[1] = (float)((mask >> (it * 4 + 1)) & 1u);
    v[2] = (float)((mask >> (it * 4 + 2)) & 1u);
    v[3] = (float)((mask >> (it * 4 + 3)) & 1u);
    __builtin_nontemporal_store(v, (f32x4*)(orow + it * 256) + lane);
  }
}

extern "C" void kernel_launch(void* const* d_in, const int* in_sizes, int n_in,
                              void* d_out, int out_size, void* d_ws, size_t ws_size,
                              hipStream_t stream) {
  const float* put = (const float*)d_in[0];
  // d_in[1] is k, fixed at 16 by setup_inputs(); hardcoded.
  float* out = (float*)d_out;

  float* norms32 = (float*)d_ws;                                  // 64 KB
  unsigned short* bhalf = (unsigned short*)((char*)d_ws + 65536); // 16.8 MB
  unsigned* Kws =
      (unsigned*)((char*)d_ws + 65536 + (size_t)NB * NN * DD * 2); // 16.8 MB

  knn_prep<<<dim3(NB * NN / 4), 256, 0, stream>>>(put, norms32, bhalf);
  knn_gemm<<<dim3(136 * NB), 256, 0, stream>>>(bhalf, norms32, Kws);
  knn_select<<<dim3((NN / 4) * NB), 256, 0, stream>>>(Kws, put, norms32, out);
}